// Round 13
// baseline (256.910 us; speedup 1.0000x reference)
//
#include <hip/hip_runtime.h>

typedef __attribute__((ext_vector_type(8))) short bf16x8;
typedef __attribute__((ext_vector_type(8))) unsigned short u16x8;
typedef __attribute__((ext_vector_type(4))) unsigned short u16x4;
typedef __attribute__((ext_vector_type(4))) float f32x4;
typedef __attribute__((ext_vector_type(16))) float f32x16;

#define MFMA32 __builtin_amdgcn_mfma_f32_32x32x16_bf16
#define MFMA16 __builtin_amdgcn_mfma_f32_16x16x32_bf16

constexpr int Bc = 4, Lc = 2048, Hc = 16, Dc = 64;
// (1/sqrt(64)) * log2(e)
constexpr float SCL = 0.18033688011112042f;

__device__ __forceinline__ unsigned short f2bf(float f) {
  unsigned u = __float_as_uint(f);
  u += 0x7fff + ((u >> 16) & 1);   // RNE
  return (unsigned short)(u >> 16);
}

__device__ __forceinline__ float fexp2(float x) {
  return __builtin_amdgcn_exp2f(x);
}

__device__ __forceinline__ unsigned cvtpk(float a, float b) {
  unsigned r;
  asm("v_cvt_pk_bf16_f32 %0, %1, %2" : "=v"(r) : "v"(a), "v"(b));
  return r;   // [15:0]=bf16(a), [31:16]=bf16(b)
}

__device__ __forceinline__ void glds16(const char* g, char* l) {
  __builtin_amdgcn_global_load_lds(
      (const __attribute__((address_space(1))) unsigned*)g,
      (__attribute__((address_space(3))) unsigned*)l, 16, 0, 0);
}

// ---------------------------------------------------------------------------
// Pre-pass: FRAGMENT-MAJOR bf16 blobs (exact LDS images, lane-linear).
//   K blob chunk (kt2,kc), lane L, 16B: K[kv0+kt2*32+(L&31)][16kc+8(L>>5)+j]
//   V blob chunk (dt2,kc), lane L, slot j:
//       V[kv0+16kc+rho(L>>5,j)][32dt2+(L&31)],  rho(hp,j)=(j&3)+4hp+8(j>>2)
//   rho makes every PV B-slot's kv-row land in the lane half that already
//   owns it after QK^T -> pf[kc] slot j = pv[8kc+j], NO shuffles.
// ---------------------------------------------------------------------------
__global__ __launch_bounds__(256)
void prep11_kernel(const float* __restrict__ Kg, const float* __restrict__ Vg,
                   char* __restrict__ KB, char* __restrict__ VB) {
  __shared__ __align__(16) short vt[64 * 80];   // V^T staging

  const int bid = blockIdx.x;
  const int bh = bid >> 5;
  const int t  = bid & 31;
  const int b  = bh >> 4;
  const int h  = bh & 15;

  const int tid = threadIdx.x;
  const int r   = tid >> 2;        // 0..63
  const int seg = (tid & 3) * 16;  // 0,16,32,48

  const size_t srow = ((size_t)((b * Lc + t * 64 + r) * Hc + h)) * Dc + seg;
  char* ktile = KB + (size_t)(bh * 32 + t) * 8192;
  char* vtile = VB + (size_t)(bh * 32 + t) * 8192;

  // ---- K: convert + fragment-major write ----
  {
    const float* kp = Kg + srow;
    float4 c0 = *reinterpret_cast<const float4*>(kp + 0);
    float4 c1 = *reinterpret_cast<const float4*>(kp + 4);
    float4 c2 = *reinterpret_cast<const float4*>(kp + 8);
    float4 c3 = *reinterpret_cast<const float4*>(kp + 12);
    union { unsigned u[4]; u16x8 v; } w0, w1;
    w0.u[0] = cvtpk(c0.x, c0.y); w0.u[1] = cvtpk(c0.z, c0.w);
    w0.u[2] = cvtpk(c1.x, c1.y); w0.u[3] = cvtpk(c1.z, c1.w);
    w1.u[0] = cvtpk(c2.x, c2.y); w1.u[1] = cvtpk(c2.z, c2.w);
    w1.u[2] = cvtpk(c3.x, c3.y); w1.u[3] = cvtpk(c3.z, c3.w);
    const int kc   = seg >> 4;
    const int kt2  = r >> 5;
    const int lane = r & 31;
    *reinterpret_cast<u16x8*>(ktile + ((kt2 * 4 + kc) * 64 + lane) * 16) = w0.v;
    *reinterpret_cast<u16x8*>(ktile + ((kt2 * 4 + kc) * 64 + lane + 32) * 16) = w1.v;
  }

  // ---- V: convert + LDS transpose ----
  {
    const float* vp = Vg + srow;
    float4 v0 = *reinterpret_cast<const float4*>(vp + 0);
    float4 v1 = *reinterpret_cast<const float4*>(vp + 4);
    float4 v2 = *reinterpret_cast<const float4*>(vp + 8);
    float4 v3 = *reinterpret_cast<const float4*>(vp + 12);
    float vv[16];
    vv[0] = v0.x; vv[1] = v0.y; vv[2] = v0.z; vv[3] = v0.w;
    vv[4] = v1.x; vv[5] = v1.y; vv[6] = v1.z; vv[7] = v1.w;
    vv[8] = v2.x; vv[9] = v2.y; vv[10] = v2.z; vv[11] = v2.w;
    vv[12] = v3.x; vv[13] = v3.y; vv[14] = v3.z; vv[15] = v3.w;
#pragma unroll
    for (int j = 0; j < 16; ++j)
      vt[(seg + j) * 80 + r] = (short)f2bf(vv[j]);
  }
  __syncthreads();

  // ---- V^T rows -> rho-permuted fragment-major write ----
  {
    const int d    = tid >> 2;
    const int kseg = (tid & 3) * 16;
    u16x4 p0 = *reinterpret_cast<const u16x4*>(vt + d * 80 + kseg + 0);   // kv +0..3
    u16x4 p1 = *reinterpret_cast<const u16x4*>(vt + d * 80 + kseg + 4);   // kv +4..7
    u16x4 p2 = *reinterpret_cast<const u16x4*>(vt + d * 80 + kseg + 8);   // kv +8..11
    u16x4 p3 = *reinterpret_cast<const u16x4*>(vt + d * 80 + kseg + 12);  // kv +12..15
    u16x8 a0, a1;
    a0[0] = p0[0]; a0[1] = p0[1]; a0[2] = p0[2]; a0[3] = p0[3];   // rho(0,j): 0..3
    a0[4] = p2[0]; a0[5] = p2[1]; a0[6] = p2[2]; a0[7] = p2[3];   //           8..11
    a1[0] = p1[0]; a1[1] = p1[1]; a1[2] = p1[2]; a1[3] = p1[3];   // rho(1,j): 4..7
    a1[4] = p3[0]; a1[5] = p3[1]; a1[6] = p3[2]; a1[7] = p3[3];   //           12..15
    const int dt2  = d >> 5;
    const int kc   = kseg >> 4;
    const int lane = d & 31;
    *reinterpret_cast<u16x8*>(vtile + ((dt2 * 4 + kc) * 64 + lane) * 16) = a0;
    *reinterpret_cast<u16x8*>(vtile + ((dt2 * 4 + kc) * 64 + lane + 32) * 16) = a1;
  }
}

// ---------------------------------------------------------------------------
// Flash attention, 32x32x16 MFMA, 8-wave blocks, q-supertile = 256,
// kv pairs per barrier (KVBLK=128). r13: __launch_bounds__(512,4) legalizes
// a 128-VGPR budget (grid is 2 blocks/CU; default 64-cap starved ILP), and
// the pair body is explicitly two-tile-pipelined: QK(t0);QK(t1) issued
// back-to-back, then SM+PV(t0) (VALU under t1's in-flight MFMAs), then
// SM+PV(t1) (VALU under t0's PV MFMAs). Per-tile math identical to r11.
// ---------------------------------------------------------------------------
__global__ __launch_bounds__(512, 4)
void fattn13_kernel(const float* __restrict__ Qg, const char* __restrict__ KB,
                    const char* __restrict__ VB, float* __restrict__ Og) {
  __shared__ __align__(128) char smem[65536];   // 2 bufs x (K 16K + V 16K)

  // 512 blocks: head = p & 63 (XCD-local since 64 % 8 == 0), qt = 7-(p>>6) LPT.
  const int p    = blockIdx.x;
  const int head = p & 63;
  const int qt   = 7 - (p >> 6);
  const int b    = head >> 4;
  const int h    = head & 15;

  const int tid = threadIdx.x;
  const int w   = tid >> 6;        // wave 0..7
  const int l   = tid & 63;
  const int q5  = l & 31;
  const int hp  = l >> 5;          // half 0/1

  const int qrow = qt * 256 + w * 32 + q5;
  const int qmin = qt * 256 + w * 32;
  const int qmax = qmin + 31;

  // ---- Q fragments (B operand: lane q=l&31, k-dim d=16kc+8hp+j), pre-scaled ----
  bf16x8 qf[4];
  {
    const float* qp = Qg + ((size_t)((b * Lc + qrow) * Hc + h)) * Dc;
#pragma unroll
    for (int kc = 0; kc < 4; ++kc) {
      const int d0 = kc * 16 + hp * 8;
      float4 a = *reinterpret_cast<const float4*>(qp + d0);
      float4 bb = *reinterpret_cast<const float4*>(qp + d0 + 4);
      union { unsigned u[4]; bf16x8 v; } f;
      f.u[0] = cvtpk(a.x * SCL, a.y * SCL);
      f.u[1] = cvtpk(a.z * SCL, a.w * SCL);
      f.u[2] = cvtpk(bb.x * SCL, bb.y * SCL);
      f.u[3] = cvtpk(bb.z * SCL, bb.w * SCL);
      qf[kc] = f.v;
    }
  }

  f32x16 o0, o1;
#pragma unroll
  for (int i = 0; i < 16; ++i) { o0[i] = 0.f; o1[i] = 0.f; }
  float m_run = -3.0e38f, l_run = 0.0f;   // l_run PER-HALF; combined at end

  const char* kbase = KB + ((size_t)head * 32) * 8192;
  const char* vbase = VB + ((size_t)head * 32) * 8192;
  const int to = tid * 16;         // per-lane global offset (0..8176)
  const int wl = w * 1024;         // wave-uniform LDS base offset

  // One pair (2 consecutive 8KB tiles, contiguous in the blob): 4 glds16.
  auto stage = [&](int bufi, int kp) {
    const char* kb = kbase + (size_t)kp * 16384;
    const char* vb = vbase + (size_t)kp * 16384;
    char* dK = smem + bufi * 32768;
    char* dV = dK + 16384;
    glds16(kb + to, dK + wl);
    glds16(kb + 8192 + to, dK + 8192 + wl);
    glds16(vb + to, dV + wl);
    glds16(vb + 8192 + to, dV + 8192 + wl);
  };

  // SM + PV for one tile, given its QK result (s0,s1). r11-proven math.
  auto sm_pv = [&](f32x16& s0, f32x16& s1, int kv0, const char* smV) {
    float pv[32];
#pragma unroll
    for (int g = 0; g < 16; ++g) { pv[g] = s0[g]; pv[16 + g] = s1[g]; }

    if (kv0 + 63 > qmin) {
#pragma unroll
      for (int g = 0; g < 32; ++g) {
        const int k = (g & 3) + 8 * ((g >> 2) & 3) + 4 * hp + 32 * (g >> 4);
        if (kv0 + k > qrow) pv[g] = -3.0e38f;
      }
    }

    float vmax = pv[0];
#pragma unroll
    for (int g = 1; g < 32; ++g) vmax = fmaxf(vmax, pv[g]);
    vmax = fmaxf(vmax, __shfl_xor(vmax, 32));
    if (!__all(vmax <= m_run + 8.0f)) {    // P bounded by 2^8; f32 accum safe
      const float m_new = fmaxf(m_run, vmax);
      const float alpha = fexp2(m_run - m_new);
      l_run *= alpha;
      m_run = m_new;
#pragma unroll
      for (int i = 0; i < 16; ++i) { o0[i] *= alpha; o1[i] *= alpha; }
    }

    float rsum = 0.f;
#pragma unroll
    for (int g = 0; g < 32; ++g) { pv[g] = fexp2(pv[g] - m_run); rsum += pv[g]; }
    l_run += rsum;                 // per-half; combined once at epilogue

    bf16x8 pf[4];
#pragma unroll
    for (int kc = 0; kc < 4; ++kc) {
      const int G = 8 * kc;
      union { unsigned u[4]; bf16x8 v; } f;
      f.u[0] = cvtpk(pv[G + 0], pv[G + 1]);
      f.u[1] = cvtpk(pv[G + 2], pv[G + 3]);
      f.u[2] = cvtpk(pv[G + 4], pv[G + 5]);
      f.u[3] = cvtpk(pv[G + 6], pv[G + 7]);
      pf[kc] = f.v;
    }

#pragma unroll
    for (int kc = 0; kc < 4; ++kc) {
      bf16x8 v0 = *reinterpret_cast<const bf16x8*>(smV + (0 * 4 + kc) * 1024 + l * 16);
      bf16x8 v1 = *reinterpret_cast<const bf16x8*>(smV + (1 * 4 + kc) * 1024 + l * 16);
      o0 = MFMA32(v0, pf[kc], o0, 0, 0, 0);
      o1 = MFMA32(v1, pf[kc], o1, 0, 0, 0);
    }
  };

  const int nkp = 2 * qt + 2;      // pairs (nkt = 4qt+4 is always even)
  int buf = 0;
  stage(0, 0);

  for (int kp = 0; kp < nkp; ++kp) {
    if (kp + 1 < nkp) {
      stage(buf ^ 1, kp + 1);
      asm volatile("s_waitcnt vmcnt(4)" ::: "memory");  // current pair landed
    } else {
      asm volatile("s_waitcnt vmcnt(0)" ::: "memory");
    }
    __builtin_amdgcn_s_barrier();

    const char* bufbase = smem + buf * 32768;
    const int kv0A = (2 * kp) * 64;
    const int kv0B = (2 * kp + 1) * 64;
    const bool doA = (kv0A <= qmax);
    const bool doB = (kv0B <= qmax);   // doB implies doA

    // ---- QK for BOTH tiles, issued back-to-back (MFMA issue non-blocking) ----
    f32x16 sA0, sA1, sB0, sB1;
    if (doA) {
      const char* smK = bufbase;
#pragma unroll
      for (int i = 0; i < 16; ++i) { sA0[i] = 0.f; sA1[i] = 0.f; }
#pragma unroll
      for (int kc = 0; kc < 4; ++kc) {
        bf16x8 k0 = *reinterpret_cast<const bf16x8*>(smK + (0 * 4 + kc) * 1024 + l * 16);
        bf16x8 k1 = *reinterpret_cast<const bf16x8*>(smK + (1 * 4 + kc) * 1024 + l * 16);
        sA0 = MFMA32(k0, qf[kc], sA0, 0, 0, 0);
        sA1 = MFMA32(k1, qf[kc], sA1, 0, 0, 0);
      }
    }
    if (doB) {
      const char* smK = bufbase + 8192;
#pragma unroll
      for (int i = 0; i < 16; ++i) { sB0[i] = 0.f; sB1[i] = 0.f; }
#pragma unroll
      for (int kc = 0; kc < 4; ++kc) {
        bf16x8 k0 = *reinterpret_cast<const bf16x8*>(smK + (0 * 4 + kc) * 1024 + l * 16);
        bf16x8 k1 = *reinterpret_cast<const bf16x8*>(smK + (1 * 4 + kc) * 1024 + l * 16);
        sB0 = MFMA32(k0, qf[kc], sB0, 0, 0, 0);
        sB1 = MFMA32(k1, qf[kc], sB1, 0, 0, 0);
      }
    }

    // ---- SM+PV t0 (VALU overlaps t1's in-flight QK MFMAs), then t1 ----
    if (doA) sm_pv(sA0, sA1, kv0A, bufbase + 16384);
    if (doB) sm_pv(sB0, sB1, kv0B, bufbase + 16384 + 8192);

    __syncthreads();
    buf ^= 1;
  }

  // ---- combine halves of l, normalize + store ----
  const float l_tot = l_run + __shfl_xor(l_run, 32);
  const float inv = 1.0f / l_tot;
  float* op = Og + ((size_t)((b * Lc + qrow) * Hc + h)) * Dc;
#pragma unroll
  for (int rq = 0; rq < 4; ++rq) {
    float4 st0, st1;
    st0.x = o0[4 * rq + 0] * inv; st0.y = o0[4 * rq + 1] * inv;
    st0.z = o0[4 * rq + 2] * inv; st0.w = o0[4 * rq + 3] * inv;
    st1.x = o1[4 * rq + 0] * inv; st1.y = o1[4 * rq + 1] * inv;
    st1.z = o1[4 * rq + 2] * inv; st1.w = o1[4 * rq + 3] * inv;
    *reinterpret_cast<float4*>(op + 8 * rq + 4 * hp) = st0;
    *reinterpret_cast<float4*>(op + 32 + 8 * rq + 4 * hp) = st1;
  }
}

// ---------------------------------------------------------------------------
// Fallback (ws too small): proven self-contained kernel.
// ---------------------------------------------------------------------------
__global__ __launch_bounds__(256)
void fattn_fallback(const float* __restrict__ Qg, const float* __restrict__ Kg,
                    const float* __restrict__ Vg, float* __restrict__ Og) {
  __shared__ __align__(128) char smem[32768];
  char* smK = smem;
  char* smV = smem + 16384;

  const int bid  = blockIdx.x;
  const int head = bid >> 5;
  const int qt   = bid & 31;
  const int b    = head >> 4;
  const int h    = head & 15;
  const int q0   = qt * 64;

  const int tid = threadIdx.x;
  const int w   = tid >> 6;
  const int l   = tid & 63;
  const int lo  = l & 15;
  const int hi4 = l >> 4;

  const int qrow = q0 + w * 16 + lo;
  const float* qp = Qg + ((size_t)((b * Lc + qrow) * Hc + h)) * Dc;
  bf16x8 qf[2];
#pragma unroll
  for (int dc = 0; dc < 2; ++dc) {
    float4 a = *reinterpret_cast<const float4*>(qp + dc * 32 + hi4 * 8);
    float4 c = *reinterpret_cast<const float4*>(qp + dc * 32 + hi4 * 8 + 4);
    bf16x8 f;
    f[0] = (short)f2bf(a.x * SCL); f[1] = (short)f2bf(a.y * SCL);
    f[2] = (short)f2bf(a.z * SCL); f[3] = (short)f2bf(a.w * SCL);
    f[4] = (short)f2bf(c.x * SCL); f[5] = (short)f2bf(c.y * SCL);
    f[6] = (short)f2bf(c.z * SCL); f[7] = (short)f2bf(c.w * SCL);
    qf[dc] = f;
  }

  f32x4 o[4];
#pragma unroll
  for (int dt = 0; dt < 4; ++dt) { o[dt][0] = 0.f; o[dt][1] = 0.f; o[dt][2] = 0.f; o[dt][3] = 0.f; }
  float m_run = -3.0e38f, l_run = 0.0f;

  const int sk   = tid >> 2;
  const int sd   = (tid & 3) * 16;
  const int swzK = (sk & 7) << 4;
  const int swzA = (lo & 7) << 4;

  const int nkt = qt + 1;
  for (int kt = 0; kt < nkt; ++kt) {
    const int kv0 = kt * 64;
    __syncthreads();
    {
      const float* kpr = Kg + ((size_t)((b * Lc + kv0 + sk) * Hc + h)) * Dc + sd;
      float4 c0 = *reinterpret_cast<const float4*>(kpr + 0);
      float4 c1 = *reinterpret_cast<const float4*>(kpr + 4);
      float4 c2 = *reinterpret_cast<const float4*>(kpr + 8);
      float4 c3 = *reinterpret_cast<const float4*>(kpr + 12);
      u16x8 w0, w1;
      w0[0] = f2bf(c0.x); w0[1] = f2bf(c0.y); w0[2] = f2bf(c0.z); w0[3] = f2bf(c0.w);
      w0[4] = f2bf(c1.x); w0[5] = f2bf(c1.y); w0[6] = f2bf(c1.z); w0[7] = f2bf(c1.w);
      w1[0] = f2bf(c2.x); w1[1] = f2bf(c2.y); w1[2] = f2bf(c2.z); w1[3] = f2bf(c2.w);
      w1[4] = f2bf(c3.x); w1[5] = f2bf(c3.y); w1[6] = f2bf(c3.z); w1[7] = f2bf(c3.w);
      *reinterpret_cast<u16x8*>(smK + sk * 128 + ((sd * 2) ^ swzK)) = w0;
      *reinterpret_cast<u16x8*>(smK + sk * 128 + ((sd * 2 + 16) ^ swzK)) = w1;

      const float* vpr = Vg + ((size_t)((b * Lc + kv0 + sk) * Hc + h)) * Dc + sd;
      float4 v0 = *reinterpret_cast<const float4*>(vpr + 0);
      float4 v1 = *reinterpret_cast<const float4*>(vpr + 4);
      float4 v2 = *reinterpret_cast<const float4*>(vpr + 8);
      float4 v3 = *reinterpret_cast<const float4*>(vpr + 12);
      float vv[16];
      vv[0] = v0.x; vv[1] = v0.y; vv[2] = v0.z; vv[3] = v0.w;
      vv[4] = v1.x; vv[5] = v1.y; vv[6] = v1.z; vv[7] = v1.w;
      vv[8] = v2.x; vv[9] = v2.y; vv[10] = v2.z; vv[11] = v2.w;
      vv[12] = v3.x; vv[13] = v3.y; vv[14] = v3.z; vv[15] = v3.w;
#pragma unroll
      for (int j = 0; j < 16; ++j) {
        const int d = sd + j;
        *reinterpret_cast<unsigned short*>(smV + d * 128 + ((sk * 2) ^ ((j & 7) << 4))) = f2bf(vv[j]);
      }
    }
    __syncthreads();

    f32x4 s[4];
#pragma unroll
    for (int ks = 0; ks < 4; ++ks) {
      const int rb = (ks * 16 + lo) * 128;
      bf16x8 a0 = *reinterpret_cast<const bf16x8*>(smK + rb + ((hi4 * 16) ^ swzA));
      bf16x8 a1 = *reinterpret_cast<const bf16x8*>(smK + rb + ((64 + hi4 * 16) ^ swzA));
      f32x4 c; c[0] = 0.f; c[1] = 0.f; c[2] = 0.f; c[3] = 0.f;
      c = MFMA16(a0, qf[0], c, 0, 0, 0);
      c = MFMA16(a1, qf[1], c, 0, 0, 0);
      s[ks] = c;
    }

    const bool diag = (kt == nkt - 1);
    float vmax = -3.0e38f;
#pragma unroll
    for (int ks = 0; ks < 4; ++ks) {
#pragma unroll
      for (int i = 0; i < 4; ++i) {
        float x = s[ks][i];
        if (diag) {
          const int kg = kv0 + ks * 16 + hi4 * 4 + i;
          if (kg > qrow) x = -3.0e38f;
        }
        s[ks][i] = x;
        vmax = fmaxf(vmax, x);
      }
    }
    vmax = fmaxf(vmax, __shfl_xor(vmax, 16));
    vmax = fmaxf(vmax, __shfl_xor(vmax, 32));
    const float m_new = fmaxf(m_run, vmax);
    const float alpha = fexp2(m_run - m_new);

    float rsum = 0.f;
    unsigned pk2[4][2];
#pragma unroll
    for (int ks = 0; ks < 4; ++ks) {
      const float p0 = fexp2(s[ks][0] - m_new);
      const float p1 = fexp2(s[ks][1] - m_new);
      const float p2 = fexp2(s[ks][2] - m_new);
      const float p3 = fexp2(s[ks][3] - m_new);
      rsum += (p0 + p1) + (p2 + p3);
      pk2[ks][0] = (unsigned)f2bf(p0) | ((unsigned)f2bf(p1) << 16);
      pk2[ks][1] = (unsigned)f2bf(p2) | ((unsigned)f2bf(p3) << 16);
    }
    rsum += __shfl_xor(rsum, 16);
    rsum += __shfl_xor(rsum, 32);
    l_run = l_run * alpha + rsum;
    m_run = m_new;
#pragma unroll
    for (int dt = 0; dt < 4; ++dt) {
      o[dt][0] *= alpha; o[dt][1] *= alpha; o[dt][2] *= alpha; o[dt][3] *= alpha;
    }

    const int srcA = lo + ((l & 16) << 1);
    const int srcB = srcA + 16;
    const bool up = (l & 32) != 0;
    bf16x8 pf[2];
#pragma unroll
    for (int c2 = 0; c2 < 2; ++c2) {
      const unsigned A0x = (unsigned)__shfl((int)pk2[2 * c2][0], srcA);
      const unsigned A0y = (unsigned)__shfl((int)pk2[2 * c2][1], srcA);
      const unsigned A1x = (unsigned)__shfl((int)pk2[2 * c2][0], srcB);
      const unsigned A1y = (unsigned)__shfl((int)pk2[2 * c2][1], srcB);
      const unsigned B0x = (unsigned)__shfl((int)pk2[2 * c2 + 1][0], srcA);
      const unsigned B0y = (unsigned)__shfl((int)pk2[2 * c2 + 1][1], srcA);
      const unsigned B1x = (unsigned)__shfl((int)pk2[2 * c2 + 1][0], srcB);
      const unsigned B1y = (unsigned)__shfl((int)pk2[2 * c2 + 1][1], srcB);
      union { unsigned u[4]; bf16x8 v; } cvt;
      cvt.u[0] = up ? B0x : A0x;
      cvt.u[1] = up ? B0y : A0y;
      cvt.u[2] = up ? B1x : A1x;
      cvt.u[3] = up ? B1y : A1y;
      pf[c2] = cvt.v;
    }

#pragma unroll
    for (int dt = 0; dt < 4; ++dt) {
      const int rb = (dt * 16 + lo) * 128;
#pragma unroll
      for (int c2 = 0; c2 < 2; ++c2) {
        bf16x8 vf = *reinterpret_cast<const bf16x8*>(smV + rb + ((c2 * 64 + hi4 * 16) ^ swzA));
        o[dt] = MFMA16(vf, pf[c2], o[dt], 0, 0, 0);
      }
    }
  }

  const float inv = 1.0f / l_run;
  float* op = Og + ((size_t)((b * Lc + qrow) * Hc + h)) * Dc;
#pragma unroll
  for (int dt = 0; dt < 4; ++dt) {
    float4 st;
    st.x = o[dt][0] * inv; st.y = o[dt][1] * inv;
    st.z = o[dt][2] * inv; st.w = o[dt][3] * inv;
    *reinterpret_cast<float4*>(op + dt * 16 + hi4 * 4) = st;
  }
}

extern "C" void kernel_launch(void* const* d_in, const int* in_sizes, int n_in,
                              void* d_out, int out_size, void* d_ws, size_t ws_size,
                              hipStream_t stream) {
  const float* Qg = (const float*)d_in[0];
  const float* Kg = (const float*)d_in[1];
  const float* Vg = (const float*)d_in[2];
  float* Og = (float*)d_out;

  const size_t blob_bytes = (size_t)64 * 32 * 8192;   // 16.78 MB per tensor
  if (ws_size >= 2 * blob_bytes) {
    char* KB = (char*)d_ws;
    char* VB = KB + blob_bytes;
    hipLaunchKernelGGL(prep11_kernel, dim3(2048), dim3(256), 0, stream, Kg, Vg, KB, VB);
    hipLaunchKernelGGL(fattn13_kernel, dim3(512), dim3(512), 0, stream, Qg, KB, VB, Og);
  } else {
    hipLaunchKernelGGL(fattn_fallback, dim3(2048), dim3(256), 0, stream, Qg, Kg, Vg, Og);
  }
}

// Round 14
// 73.837 us; speedup vs baseline: 3.4794x; 3.4794x over previous
//
#include <hip/hip_runtime.h>

typedef __attribute__((ext_vector_type(8))) short bf16x8;
typedef __attribute__((ext_vector_type(8))) unsigned short u16x8;
typedef __attribute__((ext_vector_type(4))) unsigned short u16x4;
typedef __attribute__((ext_vector_type(4))) float f32x4;
typedef __attribute__((ext_vector_type(16))) float f32x16;

#define MFMA32 __builtin_amdgcn_mfma_f32_32x32x16_bf16
#define MFMA16 __builtin_amdgcn_mfma_f32_16x16x32_bf16

constexpr int Bc = 4, Lc = 2048, Hc = 16, Dc = 64;
// (1/sqrt(64)) * log2(e)
constexpr float SCL = 0.18033688011112042f;

__device__ __forceinline__ unsigned short f2bf(float f) {
  unsigned u = __float_as_uint(f);
  u += 0x7fff + ((u >> 16) & 1);   // RNE
  return (unsigned short)(u >> 16);
}

__device__ __forceinline__ float fexp2(float x) {
  return __builtin_amdgcn_exp2f(x);
}

__device__ __forceinline__ unsigned cvtpk(float a, float b) {
  unsigned r;
  asm("v_cvt_pk_bf16_f32 %0, %1, %2" : "=v"(r) : "v"(a), "v"(b));
  return r;   // [15:0]=bf16(a), [31:16]=bf16(b)
}

__device__ __forceinline__ void glds16(const char* g, char* l) {
  __builtin_amdgcn_global_load_lds(
      (const __attribute__((address_space(1))) unsigned*)g,
      (__attribute__((address_space(3))) unsigned*)l, 16, 0, 0);
}

// ---------------------------------------------------------------------------
// Pre-pass: FRAGMENT-MAJOR bf16 blobs (exact LDS images, lane-linear).
//   K blob chunk (kt2,kc), lane L, 16B: K[kv0+kt2*32+(L&31)][16kc+8(L>>5)+j]
//   V blob chunk (dt2,kc), lane L, slot j:
//       V[kv0+16kc+rho(L>>5,j)][32dt2+(L&31)],  rho(hp,j)=(j&3)+4hp+8(j>>2)
//   rho makes every PV B-slot's kv-row land in the lane half that already
//   owns it after QK^T -> pf[kc] slot j = pv[8kc+j], NO shuffles.
// ---------------------------------------------------------------------------
__global__ __launch_bounds__(256)
void prep11_kernel(const float* __restrict__ Kg, const float* __restrict__ Vg,
                   char* __restrict__ KB, char* __restrict__ VB) {
  __shared__ __align__(16) short vt[64 * 80];   // V^T staging

  const int bid = blockIdx.x;
  const int bh = bid >> 5;
  const int t  = bid & 31;
  const int b  = bh >> 4;
  const int h  = bh & 15;

  const int tid = threadIdx.x;
  const int r   = tid >> 2;        // 0..63
  const int seg = (tid & 3) * 16;  // 0,16,32,48

  const size_t srow = ((size_t)((b * Lc + t * 64 + r) * Hc + h)) * Dc + seg;
  char* ktile = KB + (size_t)(bh * 32 + t) * 8192;
  char* vtile = VB + (size_t)(bh * 32 + t) * 8192;

  // ---- K: convert + fragment-major write ----
  {
    const float* kp = Kg + srow;
    float4 c0 = *reinterpret_cast<const float4*>(kp + 0);
    float4 c1 = *reinterpret_cast<const float4*>(kp + 4);
    float4 c2 = *reinterpret_cast<const float4*>(kp + 8);
    float4 c3 = *reinterpret_cast<const float4*>(kp + 12);
    union { unsigned u[4]; u16x8 v; } w0, w1;
    w0.u[0] = cvtpk(c0.x, c0.y); w0.u[1] = cvtpk(c0.z, c0.w);
    w0.u[2] = cvtpk(c1.x, c1.y); w0.u[3] = cvtpk(c1.z, c1.w);
    w1.u[0] = cvtpk(c2.x, c2.y); w1.u[1] = cvtpk(c2.z, c2.w);
    w1.u[2] = cvtpk(c3.x, c3.y); w1.u[3] = cvtpk(c3.z, c3.w);
    const int kc   = seg >> 4;
    const int kt2  = r >> 5;
    const int lane = r & 31;
    *reinterpret_cast<u16x8*>(ktile + ((kt2 * 4 + kc) * 64 + lane) * 16) = w0.v;
    *reinterpret_cast<u16x8*>(ktile + ((kt2 * 4 + kc) * 64 + lane + 32) * 16) = w1.v;
  }

  // ---- V: convert + LDS transpose ----
  {
    const float* vp = Vg + srow;
    float4 v0 = *reinterpret_cast<const float4*>(vp + 0);
    float4 v1 = *reinterpret_cast<const float4*>(vp + 4);
    float4 v2 = *reinterpret_cast<const float4*>(vp + 8);
    float4 v3 = *reinterpret_cast<const float4*>(vp + 12);
    float vv[16];
    vv[0] = v0.x; vv[1] = v0.y; vv[2] = v0.z; vv[3] = v0.w;
    vv[4] = v1.x; vv[5] = v1.y; vv[6] = v1.z; vv[7] = v1.w;
    vv[8] = v2.x; vv[9] = v2.y; vv[10] = v2.z; vv[11] = v2.w;
    vv[12] = v3.x; vv[13] = v3.y; vv[14] = v3.z; vv[15] = v3.w;
#pragma unroll
    for (int j = 0; j < 16; ++j)
      vt[(seg + j) * 80 + r] = (short)f2bf(vv[j]);
  }
  __syncthreads();

  // ---- V^T rows -> rho-permuted fragment-major write ----
  {
    const int d    = tid >> 2;
    const int kseg = (tid & 3) * 16;
    u16x4 p0 = *reinterpret_cast<const u16x4*>(vt + d * 80 + kseg + 0);   // kv +0..3
    u16x4 p1 = *reinterpret_cast<const u16x4*>(vt + d * 80 + kseg + 4);   // kv +4..7
    u16x4 p2 = *reinterpret_cast<const u16x4*>(vt + d * 80 + kseg + 8);   // kv +8..11
    u16x4 p3 = *reinterpret_cast<const u16x4*>(vt + d * 80 + kseg + 12);  // kv +12..15
    u16x8 a0, a1;
    a0[0] = p0[0]; a0[1] = p0[1]; a0[2] = p0[2]; a0[3] = p0[3];   // rho(0,j): 0..3
    a0[4] = p2[0]; a0[5] = p2[1]; a0[6] = p2[2]; a0[7] = p2[3];   //           8..11
    a1[0] = p1[0]; a1[1] = p1[1]; a1[2] = p1[2]; a1[3] = p1[3];   // rho(1,j): 4..7
    a1[4] = p3[0]; a1[5] = p3[1]; a1[6] = p3[2]; a1[7] = p3[3];   //           12..15
    const int dt2  = d >> 5;
    const int kc   = kseg >> 4;
    const int lane = d & 31;
    *reinterpret_cast<u16x8*>(vtile + ((dt2 * 4 + kc) * 64 + lane) * 16) = a0;
    *reinterpret_cast<u16x8*>(vtile + ((dt2 * 4 + kc) * 64 + lane + 32) * 16) = a1;
  }
}

// ---------------------------------------------------------------------------
// Flash attention, 32x32x16 MFMA, 8-wave blocks (512 thr), q-supertile = 256.
// r14 = r11 (proven) with COMPLEMENTARY per-CU qt pairing: with 512 blocks
// all co-resident (2/CU), block p and p+256 share a CU; mapping
// p<256 -> qt=7-(p>>6), p>=256 -> qt=(p>>6)-4 pairs (7,0),(6,1),(5,2),(4,3)
// = exactly 36 tile-units per CU (r11's (7,3),(6,2).. gave 48 on the
// critical CU -> 30% occupancy). head = p & 63 keeps XCD locality.
// ---------------------------------------------------------------------------
__global__ __launch_bounds__(512)
void fattn14_kernel(const float* __restrict__ Qg, const char* __restrict__ KB,
                    const char* __restrict__ VB, float* __restrict__ Og) {
  __shared__ __align__(128) char smem[32768];   // 2 bufs x (K 8K + V 8K)

  const int p    = blockIdx.x;
  const int head = p & 63;
  const int qt   = (p < 256) ? (7 - (p >> 6)) : ((p >> 6) - 4);
  const int b    = head >> 4;
  const int h    = head & 15;

  const int tid = threadIdx.x;
  const int w   = tid >> 6;        // wave 0..7
  const int l   = tid & 63;
  const int q5  = l & 31;
  const int hp  = l >> 5;          // half 0/1

  const int qrow = qt * 256 + w * 32 + q5;
  const int qmin = qt * 256 + w * 32;
  const int qmax = qmin + 31;

  // ---- Q fragments (B operand: lane q=l&31, k-dim d=16kc+8hp+j), pre-scaled ----
  bf16x8 qf[4];
  {
    const float* qp = Qg + ((size_t)((b * Lc + qrow) * Hc + h)) * Dc;
#pragma unroll
    for (int kc = 0; kc < 4; ++kc) {
      const int d0 = kc * 16 + hp * 8;
      float4 a = *reinterpret_cast<const float4*>(qp + d0);
      float4 bb = *reinterpret_cast<const float4*>(qp + d0 + 4);
      union { unsigned u[4]; bf16x8 v; } f;
      f.u[0] = cvtpk(a.x * SCL, a.y * SCL);
      f.u[1] = cvtpk(a.z * SCL, a.w * SCL);
      f.u[2] = cvtpk(bb.x * SCL, bb.y * SCL);
      f.u[3] = cvtpk(bb.z * SCL, bb.w * SCL);
      qf[kc] = f.v;
    }
  }

  f32x16 o0, o1;
#pragma unroll
  for (int i = 0; i < 16; ++i) { o0[i] = 0.f; o1[i] = 0.f; }
  float m_run = -3.0e38f, l_run = 0.0f;   // l_run PER-HALF; combined at end

  const char* kbase = KB + ((size_t)head * 32) * 8192;
  const char* vbase = VB + ((size_t)head * 32) * 8192;
  const int to = tid * 16;         // per-lane global offset (0..8176)
  const int wl = w * 1024;         // wave-uniform LDS base offset

  auto stage = [&](int bufi, int kt) {
    const char* kb = kbase + (size_t)kt * 8192;
    const char* vb = vbase + (size_t)kt * 8192;
    char* dK = smem + bufi * 16384;
    char* dV = dK + 8192;
    glds16(kb + to, dK + wl);
    glds16(vb + to, dV + wl);
  };

  const int nkt = 4 * qt + 4;
  int buf = 0;
  stage(0, 0);

  for (int kt = 0; kt < nkt; ++kt) {
    if (kt + 1 < nkt) {
      stage(buf ^ 1, kt + 1);
      asm volatile("s_waitcnt vmcnt(2)" ::: "memory");  // current tile landed
    } else {
      asm volatile("s_waitcnt vmcnt(0)" ::: "memory");
    }
    __builtin_amdgcn_s_barrier();

    const int kv0 = kt * 64;
    if (kv0 <= qmax) {               // wave-uniform skip of fully-masked tiles
      const char* smK = smem + buf * 16384;
      const char* smV = smK + 8192;

      // ---- S^T = K * Q^T (2 kv-subtiles of 32) ----
      f32x16 s0, s1;
#pragma unroll
      for (int i = 0; i < 16; ++i) { s0[i] = 0.f; s1[i] = 0.f; }
#pragma unroll
      for (int kc = 0; kc < 4; ++kc) {
        bf16x8 k0 = *reinterpret_cast<const bf16x8*>(smK + (0 * 4 + kc) * 1024 + l * 16);
        bf16x8 k1 = *reinterpret_cast<const bf16x8*>(smK + (1 * 4 + kc) * 1024 + l * 16);
        s0 = MFMA32(k0, qf[kc], s0, 0, 0, 0);
        s1 = MFMA32(k1, qf[kc], s1, 0, 0, 0);
      }

      float pv[32];
#pragma unroll
      for (int g = 0; g < 16; ++g) { pv[g] = s0[g]; pv[16 + g] = s1[g]; }

      // ---- causal mask (kv row = (g&3)+8*((g>>2)&3)+4hp+32*(g>>4)) ----
      if (kv0 + 63 > qmin) {
#pragma unroll
        for (int g = 0; g < 32; ++g) {
          const int k = (g & 3) + 8 * ((g >> 2) & 3) + 4 * hp + 32 * (g >> 4);
          if (kv0 + k > qrow) pv[g] = -3.0e38f;
        }
      }

      // ---- online softmax with defer-max (T13) ----
      float vmax = pv[0];
#pragma unroll
      for (int g = 1; g < 32; ++g) vmax = fmaxf(vmax, pv[g]);
      vmax = fmaxf(vmax, __shfl_xor(vmax, 32));
      if (!__all(vmax <= m_run + 8.0f)) {   // P bounded by 2^8; f32 accum safe
        const float m_new = fmaxf(m_run, vmax);
        const float alpha = fexp2(m_run - m_new);
        l_run *= alpha;
        m_run = m_new;
#pragma unroll
        for (int i = 0; i < 16; ++i) { o0[i] *= alpha; o1[i] *= alpha; }
      }

      float rsum = 0.f;
#pragma unroll
      for (int g = 0; g < 32; ++g) { pv[g] = fexp2(pv[g] - m_run); rsum += pv[g]; }
      l_run += rsum;                 // per-half; combined once at epilogue

      // ---- P -> PV B-fragments: straight register run (rho-permuted V) ----
      bf16x8 pf[4];
#pragma unroll
      for (int kc = 0; kc < 4; ++kc) {
        const int G = 8 * kc;
        union { unsigned u[4]; bf16x8 v; } f;
        f.u[0] = cvtpk(pv[G + 0], pv[G + 1]);
        f.u[1] = cvtpk(pv[G + 2], pv[G + 3]);
        f.u[2] = cvtpk(pv[G + 4], pv[G + 5]);
        f.u[3] = cvtpk(pv[G + 6], pv[G + 7]);
        pf[kc] = f.v;
      }

      // ---- O^T += V^T * P^T ----
#pragma unroll
      for (int kc = 0; kc < 4; ++kc) {
        bf16x8 v0 = *reinterpret_cast<const bf16x8*>(smV + (0 * 4 + kc) * 1024 + l * 16);
        bf16x8 v1 = *reinterpret_cast<const bf16x8*>(smV + (1 * 4 + kc) * 1024 + l * 16);
        o0 = MFMA32(v0, pf[kc], o0, 0, 0, 0);
        o1 = MFMA32(v1, pf[kc], o1, 0, 0, 0);
      }
    }

    __syncthreads();
    buf ^= 1;
  }

  // ---- combine halves of l, normalize + store ----
  const float l_tot = l_run + __shfl_xor(l_run, 32);
  const float inv = 1.0f / l_tot;
  float* op = Og + ((size_t)((b * Lc + qrow) * Hc + h)) * Dc;
#pragma unroll
  for (int rq = 0; rq < 4; ++rq) {
    float4 st0, st1;
    st0.x = o0[4 * rq + 0] * inv; st0.y = o0[4 * rq + 1] * inv;
    st0.z = o0[4 * rq + 2] * inv; st0.w = o0[4 * rq + 3] * inv;
    st1.x = o1[4 * rq + 0] * inv; st1.y = o1[4 * rq + 1] * inv;
    st1.z = o1[4 * rq + 2] * inv; st1.w = o1[4 * rq + 3] * inv;
    *reinterpret_cast<float4*>(op + 8 * rq + 4 * hp) = st0;
    *reinterpret_cast<float4*>(op + 32 + 8 * rq + 4 * hp) = st1;
  }
}

// ---------------------------------------------------------------------------
// Fallback (ws too small): proven self-contained kernel.
// ---------------------------------------------------------------------------
__global__ __launch_bounds__(256)
void fattn_fallback(const float* __restrict__ Qg, const float* __restrict__ Kg,
                    const float* __restrict__ Vg, float* __restrict__ Og) {
  __shared__ __align__(128) char smem[32768];
  char* smK = smem;
  char* smV = smem + 16384;

  const int bid  = blockIdx.x;
  const int head = bid >> 5;
  const int qt   = bid & 31;
  const int b    = head >> 4;
  const int h    = head & 15;
  const int q0   = qt * 64;

  const int tid = threadIdx.x;
  const int w   = tid >> 6;
  const int l   = tid & 63;
  const int lo  = l & 15;
  const int hi4 = l >> 4;

  const int qrow = q0 + w * 16 + lo;
  const float* qp = Qg + ((size_t)((b * Lc + qrow) * Hc + h)) * Dc;
  bf16x8 qf[2];
#pragma unroll
  for (int dc = 0; dc < 2; ++dc) {
    float4 a = *reinterpret_cast<const float4*>(qp + dc * 32 + hi4 * 8);
    float4 c = *reinterpret_cast<const float4*>(qp + dc * 32 + hi4 * 8 + 4);
    bf16x8 f;
    f[0] = (short)f2bf(a.x * SCL); f[1] = (short)f2bf(a.y * SCL);
    f[2] = (short)f2bf(a.z * SCL); f[3] = (short)f2bf(a.w * SCL);
    f[4] = (short)f2bf(c.x * SCL); f[5] = (short)f2bf(c.y * SCL);
    f[6] = (short)f2bf(c.z * SCL); f[7] = (short)f2bf(c.w * SCL);
    qf[dc] = f;
  }

  f32x4 o[4];
#pragma unroll
  for (int dt = 0; dt < 4; ++dt) { o[dt][0] = 0.f; o[dt][1] = 0.f; o[dt][2] = 0.f; o[dt][3] = 0.f; }
  float m_run = -3.0e38f, l_run = 0.0f;

  const int sk   = tid >> 2;
  const int sd   = (tid & 3) * 16;
  const int swzK = (sk & 7) << 4;
  const int swzA = (lo & 7) << 4;

  const int nkt = qt + 1;
  for (int kt = 0; kt < nkt; ++kt) {
    const int kv0 = kt * 64;
    __syncthreads();
    {
      const float* kpr = Kg + ((size_t)((b * Lc + kv0 + sk) * Hc + h)) * Dc + sd;
      float4 c0 = *reinterpret_cast<const float4*>(kpr + 0);
      float4 c1 = *reinterpret_cast<const float4*>(kpr + 4);
      float4 c2 = *reinterpret_cast<const float4*>(kpr + 8);
      float4 c3 = *reinterpret_cast<const float4*>(kpr + 12);
      u16x8 w0, w1;
      w0[0] = f2bf(c0.x); w0[1] = f2bf(c0.y); w0[2] = f2bf(c0.z); w0[3] = f2bf(c0.w);
      w0[4] = f2bf(c1.x); w0[5] = f2bf(c1.y); w0[6] = f2bf(c1.z); w0[7] = f2bf(c1.w);
      w1[0] = f2bf(c2.x); w1[1] = f2bf(c2.y); w1[2] = f2bf(c2.z); w1[3] = f2bf(c2.w);
      w1[4] = f2bf(c3.x); w1[5] = f2bf(c3.y); w1[6] = f2bf(c3.z); w1[7] = f2bf(c3.w);
      *reinterpret_cast<u16x8*>(smK + sk * 128 + ((sd * 2) ^ swzK)) = w0;
      *reinterpret_cast<u16x8*>(smK + sk * 128 + ((sd * 2 + 16) ^ swzK)) = w1;

      const float* vpr = Vg + ((size_t)((b * Lc + kv0 + sk) * Hc + h)) * Dc + sd;
      float4 v0 = *reinterpret_cast<const float4*>(vpr + 0);
      float4 v1 = *reinterpret_cast<const float4*>(vpr + 4);
      float4 v2 = *reinterpret_cast<const float4*>(vpr + 8);
      float4 v3 = *reinterpret_cast<const float4*>(vpr + 12);
      float vv[16];
      vv[0] = v0.x; vv[1] = v0.y; vv[2] = v0.z; vv[3] = v0.w;
      vv[4] = v1.x; vv[5] = v1.y; vv[6] = v1.z; vv[7] = v1.w;
      vv[8] = v2.x; vv[9] = v2.y; vv[10] = v2.z; vv[11] = v2.w;
      vv[12] = v3.x; vv[13] = v3.y; vv[14] = v3.z; vv[15] = v3.w;
#pragma unroll
      for (int j = 0; j < 16; ++j) {
        const int d = sd + j;
        *reinterpret_cast<unsigned short*>(smV + d * 128 + ((sk * 2) ^ ((j & 7) << 4))) = f2bf(vv[j]);
      }
    }
    __syncthreads();

    f32x4 s[4];
#pragma unroll
    for (int ks = 0; ks < 4; ++ks) {
      const int rb = (ks * 16 + lo) * 128;
      bf16x8 a0 = *reinterpret_cast<const bf16x8*>(smK + rb + ((hi4 * 16) ^ swzA));
      bf16x8 a1 = *reinterpret_cast<const bf16x8*>(smK + rb + ((64 + hi4 * 16) ^ swzA));
      f32x4 c; c[0] = 0.f; c[1] = 0.f; c[2] = 0.f; c[3] = 0.f;
      c = MFMA16(a0, qf[0], c, 0, 0, 0);
      c = MFMA16(a1, qf[1], c, 0, 0, 0);
      s[ks] = c;
    }

    const bool diag = (kt == nkt - 1);
    float vmax = -3.0e38f;
#pragma unroll
    for (int ks = 0; ks < 4; ++ks) {
#pragma unroll
      for (int i = 0; i < 4; ++i) {
        float x = s[ks][i];
        if (diag) {
          const int kg = kv0 + ks * 16 + hi4 * 4 + i;
          if (kg > qrow) x = -3.0e38f;
        }
        s[ks][i] = x;
        vmax = fmaxf(vmax, x);
      }
    }
    vmax = fmaxf(vmax, __shfl_xor(vmax, 16));
    vmax = fmaxf(vmax, __shfl_xor(vmax, 32));
    const float m_new = fmaxf(m_run, vmax);
    const float alpha = fexp2(m_run - m_new);

    float rsum = 0.f;
    unsigned pk2[4][2];
#pragma unroll
    for (int ks = 0; ks < 4; ++ks) {
      const float p0 = fexp2(s[ks][0] - m_new);
      const float p1 = fexp2(s[ks][1] - m_new);
      const float p2 = fexp2(s[ks][2] - m_new);
      const float p3 = fexp2(s[ks][3] - m_new);
      rsum += (p0 + p1) + (p2 + p3);
      pk2[ks][0] = (unsigned)f2bf(p0) | ((unsigned)f2bf(p1) << 16);
      pk2[ks][1] = (unsigned)f2bf(p2) | ((unsigned)f2bf(p3) << 16);
    }
    rsum += __shfl_xor(rsum, 16);
    rsum += __shfl_xor(rsum, 32);
    l_run = l_run * alpha + rsum;
    m_run = m_new;
#pragma unroll
    for (int dt = 0; dt < 4; ++dt) {
      o[dt][0] *= alpha; o[dt][1] *= alpha; o[dt][2] *= alpha; o[dt][3] *= alpha;
    }

    const int srcA = lo + ((l & 16) << 1);
    const int srcB = srcA + 16;
    const bool up = (l & 32) != 0;
    bf16x8 pf[2];
#pragma unroll
    for (int c2 = 0; c2 < 2; ++c2) {
      const unsigned A0x = (unsigned)__shfl((int)pk2[2 * c2][0], srcA);
      const unsigned A0y = (unsigned)__shfl((int)pk2[2 * c2][1], srcA);
      const unsigned A1x = (unsigned)__shfl((int)pk2[2 * c2][0], srcB);
      const unsigned A1y = (unsigned)__shfl((int)pk2[2 * c2][1], srcB);
      const unsigned B0x = (unsigned)__shfl((int)pk2[2 * c2 + 1][0], srcA);
      const unsigned B0y = (unsigned)__shfl((int)pk2[2 * c2 + 1][1], srcA);
      const unsigned B1x = (unsigned)__shfl((int)pk2[2 * c2 + 1][0], srcB);
      const unsigned B1y = (unsigned)__shfl((int)pk2[2 * c2 + 1][1], srcB);
      union { unsigned u[4]; bf16x8 v; } cvt;
      cvt.u[0] = up ? B0x : A0x;
      cvt.u[1] = up ? B0y : A0y;
      cvt.u[2] = up ? B1x : A1x;
      cvt.u[3] = up ? B1y : A1y;
      pf[c2] = cvt.v;
    }

#pragma unroll
    for (int dt = 0; dt < 4; ++dt) {
      const int rb = (dt * 16 + lo) * 128;
#pragma unroll
      for (int c2 = 0; c2 < 2; ++c2) {
        bf16x8 vf = *reinterpret_cast<const bf16x8*>(smV + rb + ((c2 * 64 + hi4 * 16) ^ swzA));
        o[dt] = MFMA16(vf, pf[c2], o[dt], 0, 0, 0);
      }
    }
  }

  const float inv = 1.0f / l_run;
  float* op = Og + ((size_t)((b * Lc + qrow) * Hc + h)) * Dc;
#pragma unroll
  for (int dt = 0; dt < 4; ++dt) {
    float4 st;
    st.x = o[dt][0] * inv; st.y = o[dt][1] * inv;
    st.z = o[dt][2] * inv; st.w = o[dt][3] * inv;
    *reinterpret_cast<float4*>(op + dt * 16 + hi4 * 4) = st;
  }
}

extern "C" void kernel_launch(void* const* d_in, const int* in_sizes, int n_in,
                              void* d_out, int out_size, void* d_ws, size_t ws_size,
                              hipStream_t stream) {
  const float* Qg = (const float*)d_in[0];
  const float* Kg = (const float*)d_in[1];
  const float* Vg = (const float*)d_in[2];
  float* Og = (float*)d_out;

  const size_t blob_bytes = (size_t)64 * 32 * 8192;   // 16.78 MB per tensor
  if (ws_size >= 2 * blob_bytes) {
    char* KB = (char*)d_ws;
    char* VB = KB + blob_bytes;
    hipLaunchKernelGGL(prep11_kernel, dim3(2048), dim3(256), 0, stream, Kg, Vg, KB, VB);
    hipLaunchKernelGGL(fattn14_kernel, dim3(512), dim3(512), 0, stream, Qg, KB, VB, Og);
  } else {
    hipLaunchKernelGGL(fattn_fallback, dim3(2048), dim3(256), 0, stream, Qg, Kg, Vg, Og);
  }
}